// Round 14
// baseline (622.319 us; speedup 1.0000x reference)
//
#include <hip/hip_runtime.h>
#include <math.h>

#define NN 100000
#define NE 1600000
#define NB 391    // ceil(NN/256) dst-buckets of 256 nodes
#define CAP 4608  // fixed bucket capacity: mean 4096, sigma 64 -> +8 sigma

typedef __attribute__((ext_vector_type(8))) short short8;
typedef __attribute__((ext_vector_type(4))) float f32x4;
union frag8 { short s[8]; short8 v; };

__device__ __forceinline__ void split_bf16(float a, short& hi, short& lo) {
    unsigned u = __float_as_uint(a);
    unsigned hb = u & 0xffff0000u;
    hi = (short)(hb >> 16);
    float r = a - __uint_as_float(hb);
    unsigned lu = __float_as_uint(r);
    lo = (short)((lu + 0x7fff + ((lu >> 16) & 1)) >> 16);
}

// ---------------- partition into fixed-capacity buckets (block-local chunk reservation) ----------------
__global__ __launch_bounds__(256) void part2_k(const int* __restrict__ src, const int* __restrict__ dst,
                                               int* bcur, int2* __restrict__ pairs, int e) {
    __shared__ int lhist[NB];
    __shared__ int lbase[NB];
    int t = threadIdx.x;
    for (int i = t; i < NB; i += 256) lhist[i] = 0;
    __syncthreads();
    int e0 = blockIdx.x * 4096;
    int sreg[16], dreg[16];
#pragma unroll
    for (int j = 0; j < 16; ++j) {
        int i = e0 + j * 256 + t;
        if (i < e) {
            sreg[j] = src[i];
            dreg[j] = dst[i];
            atomicAdd(&lhist[dreg[j] >> 8], 1);
        } else dreg[j] = -1;
    }
    __syncthreads();
    for (int i = t; i < NB; i += 256) {
        int c = lhist[i];
        lbase[i] = c ? (i * CAP + atomicAdd(&bcur[i], c)) : 0;
        lhist[i] = 0;
    }
    __syncthreads();
#pragma unroll
    for (int j = 0; j < 16; ++j) {
        if (dreg[j] >= 0) {
            int b = dreg[j] >> 8;
            int pos = lbase[b] + atomicAdd(&lhist[b], 1);
            pairs[pos] = make_int2(sreg[j], dreg[j]);
        }
    }
}

// ---------------- per-bucket (LDS-staged): count + scan + rowdesc/dinv + CSR fill ----------------
__global__ __launch_bounds__(256) void csr2_k(const int2* __restrict__ pairs, const int* __restrict__ bcur,
                                              float* __restrict__ dinv, int2* __restrict__ rowdesc,
                                              int* __restrict__ csr_src, int n) {
    __shared__ int2 lp[CAP];          // 36.9 KB
    __shared__ int cnt[256];
    __shared__ int wsum[4];
    __shared__ int lcur[256];
    int b = blockIdx.x, t = threadIdx.x;
    const int tot = bcur[b];
    const int e0 = b * CAP;
    cnt[t] = 0;
    __syncthreads();
    for (int e = t; e < tot; e += 256) {
        int2 p = pairs[e0 + e];
        lp[e] = p;
        atomicAdd(&cnt[p.y & 255], 1);
    }
    __syncthreads();
    int c = cnt[t];
    int lane = t & 63, wid = t >> 6;
    int inc = c;
#pragma unroll
    for (int off = 1; off < 64; off <<= 1) {
        int tt = __shfl_up(inc, off);
        if (lane >= off) inc += tt;
    }
    if (lane == 63) wsum[wid] = inc;
    __syncthreads();
    int woff = 0;
    for (int w = 0; w < wid; ++w) woff += wsum[w];
    int excl = inc - c + woff + e0;
    int i = (b << 8) + t;
    if (i < n) {
        rowdesc[i] = make_int2(excl, c);
        dinv[i] = 1.0f / sqrtf((float)(c + 1));
    }
    lcur[t] = excl;
    __syncthreads();
    for (int e = t; e < tot; e += 256) {
        int2 p = lp[e];
        int pos = atomicAdd(&lcur[p.y & 255], 1);
        csr_src[pos] = p.x;
    }
}

// ---------------- W pre-split (transposed bf16 hi/lo) ----------------
__global__ __launch_bounds__(256) void convw_k(const float* __restrict__ W0, const float* __restrict__ W1,
                                               const float* __restrict__ W2, const float* __restrict__ W3,
                                               short* __restrict__ wt) {
    int gid = blockIdx.x * 256 + threadIdx.x;
    if (gid >= 57344) return;
    const float* W;
    int elem, Ncols, hi_base;
    if (gid < 49152) {
        int w = gid >> 14;
        elem = gid & 16383;
        Ncols = 128;
        W = (w == 0) ? W0 : (w == 1) ? W1 : W2;
        hi_base = w * 32768;
    } else {
        elem = gid - 49152;
        Ncols = 64;
        W = W3;
        hi_base = 98304;
    }
    int k = elem / Ncols, ncol = elem % Ncols;
    short hi, lo;
    split_bf16(W[elem], hi, lo);
    int dstidx = ncol * 128 + k;
    wt[hi_base + dstidx] = hi;
    wt[hi_base + Ncols * 128 + dstidx] = lo;
}

// ---------------- MFMA GEMM (layer 0): C = (x @ W)·dinv ----------------
__global__ __launch_bounds__(256) void mfma_gemm_k(const float* __restrict__ A,
                                                   const short* __restrict__ wt_hi,
                                                   const short* __restrict__ wt_lo,
                                                   const float* __restrict__ dinv,
                                                   float* __restrict__ C, int n) {
    constexpr int NT = 8;
    const int tid = threadIdx.x;
    const int wid = tid >> 6, lane = tid & 63;
    const int arow = blockIdx.x * 64 + wid * 16 + (lane & 15);
    const int khalf = lane >> 4;

    f32x4 acc[NT];
#pragma unroll
    for (int nt = 0; nt < NT; ++nt) acc[nt] = (f32x4){0.f, 0.f, 0.f, 0.f};

#pragma unroll
    for (int kc = 0; kc < 4; ++kc) {
        const int k0 = kc * 32 + khalf * 8;
        float4 a0 = make_float4(0.f, 0.f, 0.f, 0.f), a1 = a0;
        if (arow < n) {
            a0 = *(const float4*)(A + (size_t)arow * 128 + k0);
            a1 = *(const float4*)(A + (size_t)arow * 128 + k0 + 4);
        }
        frag8 ahi, alo;
        float av[8] = {a0.x, a0.y, a0.z, a0.w, a1.x, a1.y, a1.z, a1.w};
#pragma unroll
        for (int j = 0; j < 8; ++j) split_bf16(av[j], ahi.s[j], alo.s[j]);

#pragma unroll
        for (int nt = 0; nt < NT; ++nt) {
            const size_t bidx = (size_t)(nt * 16 + (lane & 15)) * 128 + k0;
            short8 bhi = *(const short8*)(wt_hi + bidx);
            short8 blo = *(const short8*)(wt_lo + bidx);
            acc[nt] = __builtin_amdgcn_mfma_f32_16x16x32_bf16(alo.v, bhi, acc[nt], 0, 0, 0);
            acc[nt] = __builtin_amdgcn_mfma_f32_16x16x32_bf16(ahi.v, blo, acc[nt], 0, 0, 0);
            acc[nt] = __builtin_amdgcn_mfma_f32_16x16x32_bf16(ahi.v, bhi, acc[nt], 0, 0, 0);
        }
    }

    const int rbase = blockIdx.x * 64 + wid * 16 + khalf * 4;
    const int col = lane & 15;
    float dv[4];
#pragma unroll
    for (int r = 0; r < 4; ++r) dv[r] = (rbase + r < n) ? dinv[rbase + r] : 0.f;
#pragma unroll
    for (int nt = 0; nt < NT; ++nt) {
#pragma unroll
        for (int r = 0; r < 4; ++r) {
            int row = rbase + r;
            if (row < n) C[(size_t)row * 128 + nt * 16 + col] = acc[nt][r] * dv[r];
        }
    }
}

// ---------------- FUSED v8: wave-wide node groups (4 waves x 8 nodes), float2 gathers ----------------
// requires NN % 32 == 0 (100000 = 3125*32): no row guards
template<int HOUT>
__global__ __launch_bounds__(256) void fused_k(const float* __restrict__ tmp,
                                               const int* __restrict__ csr_src,
                                               const int2* __restrict__ rowdesc,
                                               const float* __restrict__ dinv,
                                               const float* __restrict__ bias,
                                               const short* __restrict__ wt_hi,
                                               const short* __restrict__ wt_lo,
                                               float* __restrict__ C) {
    constexpr int NT = HOUT / 32;
    __shared__ short Ah[32][136];    // bf16 hi plane
    __shared__ short Al[32][136];    // bf16 lo plane
    const int t = threadIdx.x;
    const int row0 = blockIdx.x * 32;

    // ---- phase 1: wave wv handles rows wv*8..wv*8+7; lane l covers cols 2l,2l+1 ----
    {
        const int wv = t >> 6;       // 0..3
        const int l  = t & 63;
        float2 bb = *(const float2*)(bias + l * 2);
        int2 rd = rowdesc[row0 + wv * 8];
        int pf = (l < rd.y) ? csr_src[rd.x + l] : 0;
#pragma unroll
        for (int it = 0; it < 8; ++it) {
            const int node = row0 + wv * 8 + it;
            const float dn = dinv[node];
            float2 acc = *(const float2*)(tmp + (size_t)node * 128 + l * 2);
            int myidx = pf;
            int e = rd.x;
            const int end = rd.x + rd.y;
            if (it < 7) {                           // issue next node's desc + first chunk NOW
                int2 rdn = rowdesc[node + 1];
                pf = (l < rdn.y) ? csr_src[rdn.x + l] : 0;
                rd = rdn;
            }
            while (e < end) {
                int m = end - e;
                if (m > 64) m = 64;
                int j = 0;
                for (; j + 4 <= m; j += 4) {
                    int s0 = __shfl(myidx, j);
                    int s1 = __shfl(myidx, j + 1);
                    int s2 = __shfl(myidx, j + 2);
                    int s3 = __shfl(myidx, j + 3);
                    float2 v0 = *(const float2*)(tmp + (size_t)s0 * 128 + l * 2);
                    float2 v1 = *(const float2*)(tmp + (size_t)s1 * 128 + l * 2);
                    float2 v2 = *(const float2*)(tmp + (size_t)s2 * 128 + l * 2);
                    float2 v3 = *(const float2*)(tmp + (size_t)s3 * 128 + l * 2);
                    acc.x += (v0.x + v1.x) + (v2.x + v3.x);
                    acc.y += (v0.y + v1.y) + (v2.y + v3.y);
                }
                for (; j < m; ++j) {
                    int s0 = __shfl(myidx, j);
                    float2 v0 = *(const float2*)(tmp + (size_t)s0 * 128 + l * 2);
                    acc.x += v0.x; acc.y += v0.y;
                }
                e += m;
                if (e < end)                         // rare continuation (deg > 64)
                    myidx = (e + l < end) ? csr_src[e + l] : 0;
            }
            acc.x = fmaxf(fmaf(acc.x, dn, bb.x), 0.f);
            acc.y = fmaxf(fmaf(acc.y, dn, bb.y), 0.f);
            short hx, lx, hy, ly;
            split_bf16(acc.x, hx, lx);
            split_bf16(acc.y, hy, ly);
            const int r = wv * 8 + it;
            short2 h2; h2.x = hx; h2.y = hy;
            short2 l2; l2.x = lx; l2.y = ly;
            *(short2*)&Ah[r][l * 2] = h2;
            *(short2*)&Al[r][l * 2] = l2;
        }
    }
    __syncthreads();

    // ---- phase 2: MFMA straight from bf16 LDS planes ----
    const int wid = t >> 6, lane = t & 63;
    const int rt = wid & 1;
    const int cg = wid >> 1;
    const int arow_l = rt * 16 + (lane & 15);
    const int khalf = lane >> 4;

    f32x4 acc[NT];
#pragma unroll
    for (int nt = 0; nt < NT; ++nt) acc[nt] = (f32x4){0.f, 0.f, 0.f, 0.f};

#pragma unroll
    for (int kc = 0; kc < 4; ++kc) {
        const int k0 = kc * 32 + khalf * 8;
        short8 ahi = *(const short8*)&Ah[arow_l][k0];
        short8 alo = *(const short8*)&Al[arow_l][k0];

#pragma unroll
        for (int nt = 0; nt < NT; ++nt) {
            const size_t bidx = (size_t)(cg * NT * 16 + nt * 16 + (lane & 15)) * 128 + k0;
            short8 bhi = *(const short8*)(wt_hi + bidx);
            short8 blo = *(const short8*)(wt_lo + bidx);
            acc[nt] = __builtin_amdgcn_mfma_f32_16x16x32_bf16(alo, bhi, acc[nt], 0, 0, 0);
            acc[nt] = __builtin_amdgcn_mfma_f32_16x16x32_bf16(ahi, blo, acc[nt], 0, 0, 0);
            acc[nt] = __builtin_amdgcn_mfma_f32_16x16x32_bf16(ahi, bhi, acc[nt], 0, 0, 0);
        }
    }

    const int rbase = row0 + rt * 16 + khalf * 4;
    const int col = lane & 15;
    float dv[4];
#pragma unroll
    for (int r = 0; r < 4; ++r) dv[r] = dinv[rbase + r];
#pragma unroll
    for (int nt = 0; nt < NT; ++nt) {
#pragma unroll
        for (int r = 0; r < 4; ++r) {
            C[(size_t)(rbase + r) * HOUT + cg * NT * 16 + nt * 16 + col] = acc[nt][r] * dv[r];
        }
    }
}

// ---------------- final gather-aggregate (HOUT=64): 2 nodes per 16-lane group, prefetch ----------------
// requires NN % 32 == 0: block of 256 covers 32 nodes
__global__ __launch_bounds__(256) void agg3_k(const float* __restrict__ tmp,
                                              const int* __restrict__ csr_src,
                                              const int2* __restrict__ rowdesc,
                                              const float* __restrict__ dinv,
                                              const float* __restrict__ bias,
                                              float* __restrict__ out) {
    const int t = threadIdx.x;
    const int l = t & 15;            // 16 lanes per group (HOUT=64 -> float4 each)
    const int g = t >> 4;            // 16 groups
    const int n0 = blockIdx.x * 32 + g * 2;

    float4 bb = *(const float4*)(bias + l * 4);
    int2 rd0 = rowdesc[n0];
    int2 rd1 = rowdesc[n0 + 1];
    int eptr[2] = {rd0.x, rd1.x};
    int eend[2] = {rd0.x + rd0.y, rd1.x + rd1.y};
    int pf = (eptr[0] + l < eend[0]) ? csr_src[eptr[0] + l] : 0;

#pragma unroll
    for (int it = 0; it < 2; ++it) {
        const int node = n0 + it;
        const float dn = dinv[node];
        float4 acc = *(const float4*)(tmp + (size_t)node * 64 + l * 4);
        int myidx = pf;
        if (it < 1)
            pf = (eptr[1] + l < eend[1]) ? csr_src[eptr[1] + l] : 0;
        int e = eptr[it];
        const int end = eend[it];
        while (e < end) {
            int m = end - e;
            if (m > 16) m = 16;
            int j = 0;
            for (; j + 4 <= m; j += 4) {
                int s0 = __shfl(myidx, j, 16);
                int s1 = __shfl(myidx, j + 1, 16);
                int s2 = __shfl(myidx, j + 2, 16);
                int s3 = __shfl(myidx, j + 3, 16);
                float4 v0 = *(const float4*)(tmp + (size_t)s0 * 64 + l * 4);
                float4 v1 = *(const float4*)(tmp + (size_t)s1 * 64 + l * 4);
                float4 v2 = *(const float4*)(tmp + (size_t)s2 * 64 + l * 4);
                float4 v3 = *(const float4*)(tmp + (size_t)s3 * 64 + l * 4);
                acc.x += (v0.x + v1.x) + (v2.x + v3.x);
                acc.y += (v0.y + v1.y) + (v2.y + v3.y);
                acc.z += (v0.z + v1.z) + (v2.z + v3.z);
                acc.w += (v0.w + v1.w) + (v2.w + v3.w);
            }
            for (; j < m; ++j) {
                int s0 = __shfl(myidx, j, 16);
                float4 v0 = *(const float4*)(tmp + (size_t)s0 * 64 + l * 4);
                acc.x += v0.x; acc.y += v0.y; acc.z += v0.z; acc.w += v0.w;
            }
            e += m;
            if (e < end)
                myidx = (e + l < end) ? csr_src[e + l] : 0;
        }
        float4 o;
        o.x = fmaf(acc.x, dn, bb.x);
        o.y = fmaf(acc.y, dn, bb.y);
        o.z = fmaf(acc.z, dn, bb.z);
        o.w = fmaf(acc.w, dn, bb.w);
        *(float4*)(out + (size_t)node * 64 + l * 4) = o;
    }
}

extern "C" void kernel_launch(void* const* d_in, const int* in_sizes, int n_in,
                              void* d_out, int out_size, void* d_ws, size_t ws_size,
                              hipStream_t stream) {
    const float* x    = (const float*)d_in[0];
    const int*   ei   = (const int*)d_in[1];
    const int*   srcp = ei;
    const int*   dstp = ei + NE;
    const float* W0 = (const float*)d_in[2]; const float* b0 = (const float*)d_in[3];
    const float* W1 = (const float*)d_in[4]; const float* b1 = (const float*)d_in[5];
    const float* W2 = (const float*)d_in[6]; const float* b2 = (const float*)d_in[7];
    const float* W3 = (const float*)d_in[8]; const float* b3 = (const float*)d_in[9];
    float* out = (float*)d_out;

    char* ws = (char*)d_ws;
    size_t off = 0;
    auto alloc = [&](size_t bytes) { void* p = ws + off; off = (off + bytes + 255) & ~(size_t)255; return p; };
    int*   bcur    = (int*)alloc((size_t)NB * 4);
    float* dinv    = (float*)alloc((size_t)NN * 4);
    int2*  rowdesc = (int2*)alloc((size_t)NN * 8);
    int*   csr_src = (int*)alloc((size_t)NB * CAP * 4);
    short* wt      = (short*)alloc((size_t)114688 * 2);
    float* bufA    = (float*)alloc((size_t)NN * 128 * 4);
    float* bufB    = (float*)alloc((size_t)NN * 128 * 4);
    int2*  pairs   = (int2*)bufA;   // alias: dead before fused writes bufA

    const int nblk_e4k = (NE + 4095) / 4096;   // 391
    const int nblk_g   = (NN + 63) / 64;       // 1563
    const int nblk_f   = NN / 32;              // 3125

    // ---- graph preprocessing: fixed-capacity bucketed CSR build ----
    hipMemsetAsync(bcur, 0, (size_t)NB * 4, stream);
    part2_k<<<nblk_e4k, 256, 0, stream>>>(srcp, dstp, bcur, pairs, NE);
    csr2_k<<<NB, 256, 0, stream>>>(pairs, bcur, dinv, rowdesc, csr_src, NN);
    convw_k<<<(57344 + 255) / 256, 256, 0, stream>>>(W0, W1, W2, W3, wt);

    const short* w0h = wt,          *w0l = wt + 16384;
    const short* w1h = wt + 32768,  *w1l = wt + 49152;
    const short* w2h = wt + 65536,  *w2l = wt + 81920;
    const short* w3h = wt + 98304,  *w3l = wt + 106496;

    // layer 0 gemm: x -> tmp0 (bufB so pairs in bufA stay live until csr2 done)
    mfma_gemm_k<<<nblk_g, 256, 0, stream>>>(x, w0h, w0l, dinv, bufB, NN);
    // fused layer0-agg + layer1 gemm: tmp0 -> tmp1
    fused_k<128><<<nblk_f, 256, 0, stream>>>(bufB, csr_src, rowdesc, dinv, b0, w1h, w1l, bufA);
    // fused layer1-agg + layer2 gemm: tmp1 -> tmp2
    fused_k<128><<<nblk_f, 256, 0, stream>>>(bufA, csr_src, rowdesc, dinv, b1, w2h, w2l, bufB);
    // fused layer2-agg + layer3 gemm: tmp2 -> tmp3
    fused_k<64><<<nblk_f, 256, 0, stream>>>(bufB, csr_src, rowdesc, dinv, b2, w3h, w3l, bufA);
    // final aggregation of tmp3 -> out
    agg3_k<<<nblk_f, 256, 0, stream>>>(bufA, csr_src, rowdesc, dinv, b3, out);
}

// Round 15
// 574.261 us; speedup vs baseline: 1.0837x; 1.0837x over previous
//
#include <hip/hip_runtime.h>
#include <math.h>

#define NN 100000
#define NE 1600000
#define NB 391    // ceil(NN/256) dst-buckets of 256 nodes
#define CAP 5120  // fixed bucket capacity incl. pad-to-4 (mean 4096+384, +8 sigma safe)

typedef __attribute__((ext_vector_type(8))) short short8;
typedef __attribute__((ext_vector_type(4))) float f32x4;
union frag8 { short s[8]; short8 v; };

__device__ __forceinline__ void split_bf16(float a, short& hi, short& lo) {
    unsigned u = __float_as_uint(a);
    unsigned hb = u & 0xffff0000u;
    hi = (short)(hb >> 16);
    float r = a - __uint_as_float(hb);
    unsigned lu = __float_as_uint(r);
    lo = (short)((lu + 0x7fff + ((lu >> 16) & 1)) >> 16);
}

// ---------------- partition into fixed-capacity buckets (block-local chunk reservation) ----------------
__global__ __launch_bounds__(256) void part2_k(const int* __restrict__ src, const int* __restrict__ dst,
                                               int* bcur, int2* __restrict__ pairs, int e) {
    __shared__ int lhist[NB];
    __shared__ int lbase[NB];
    int t = threadIdx.x;
    for (int i = t; i < NB; i += 256) lhist[i] = 0;
    __syncthreads();
    int e0 = blockIdx.x * 4096;
    int sreg[16], dreg[16];
#pragma unroll
    for (int j = 0; j < 16; ++j) {
        int i = e0 + j * 256 + t;
        if (i < e) {
            sreg[j] = src[i];
            dreg[j] = dst[i];
            atomicAdd(&lhist[dreg[j] >> 8], 1);
        } else dreg[j] = -1;
    }
    __syncthreads();
    for (int i = t; i < NB; i += 256) {
        int c = lhist[i];
        lbase[i] = c ? (i * CAP + atomicAdd(&bcur[i], c)) : 0;
        lhist[i] = 0;
    }
    __syncthreads();
#pragma unroll
    for (int j = 0; j < 16; ++j) {
        if (dreg[j] >= 0) {
            int b = dreg[j] >> 8;
            int pos = lbase[b] + atomicAdd(&lhist[b], 1);
            pairs[pos] = make_int2(sreg[j], dreg[j]);
        }
    }
}

// ---------------- per-bucket (LDS-staged): count + padded scan + rowdesc/dinv + CSR fill + pad ----------------
// edge lists padded to multiple of 4 with virtual node NN (zero row)
__global__ __launch_bounds__(256) void csr2_k(const int2* __restrict__ pairs, const int* __restrict__ bcur,
                                              float* __restrict__ dinv, int2* __restrict__ rowdesc,
                                              int* __restrict__ csr_src, int n) {
    __shared__ int2 lp[CAP];          // 40 KB
    __shared__ int cnt[256];
    __shared__ int wsum[4];
    __shared__ int lcur[256];
    int b = blockIdx.x, t = threadIdx.x;
    const int tot = bcur[b];
    const int e0 = b * CAP;
    cnt[t] = 0;
    __syncthreads();
    for (int e = t; e < tot; e += 256) {
        int2 p = pairs[e0 + e];
        lp[e] = p;
        atomicAdd(&cnt[p.y & 255], 1);
    }
    __syncthreads();
    int c = cnt[t];
    int cp = (c + 3) & ~3;            // padded to multiple of 4
    int lane = t & 63, wid = t >> 6;
    int inc = cp;
#pragma unroll
    for (int off = 1; off < 64; off <<= 1) {
        int tt = __shfl_up(inc, off);
        if (lane >= off) inc += tt;
    }
    if (lane == 63) wsum[wid] = inc;
    __syncthreads();
    int woff = 0;
    for (int w = 0; w < wid; ++w) woff += wsum[w];
    int excl = inc - cp + woff + e0;  // padded offsets within bucket region
    int i = (b << 8) + t;
    if (i < n) {
        rowdesc[i] = make_int2(excl, cp);
        dinv[i] = 1.0f / sqrtf((float)(c + 1));   // real degree
    }
    lcur[t] = excl;
    __syncthreads();
    for (int e = t; e < tot; e += 256) {
        int2 p = lp[e];
        int pos = atomicAdd(&lcur[p.y & 255], 1);
        csr_src[pos] = p.x;
    }
    // pad own node's list with virtual zero node NN
    for (int p = c; p < cp; ++p) csr_src[excl + p] = NN;
}

// ---------------- W pre-split (transposed bf16 hi/lo) ----------------
__global__ __launch_bounds__(256) void convw_k(const float* __restrict__ W0, const float* __restrict__ W1,
                                               const float* __restrict__ W2, const float* __restrict__ W3,
                                               short* __restrict__ wt) {
    int gid = blockIdx.x * 256 + threadIdx.x;
    if (gid >= 57344) return;
    const float* W;
    int elem, Ncols, hi_base;
    if (gid < 49152) {
        int w = gid >> 14;
        elem = gid & 16383;
        Ncols = 128;
        W = (w == 0) ? W0 : (w == 1) ? W1 : W2;
        hi_base = w * 32768;
    } else {
        elem = gid - 49152;
        Ncols = 64;
        W = W3;
        hi_base = 98304;
    }
    int k = elem / Ncols, ncol = elem % Ncols;
    short hi, lo;
    split_bf16(W[elem], hi, lo);
    int dstidx = ncol * 128 + k;
    wt[hi_base + dstidx] = hi;
    wt[hi_base + Ncols * 128 + dstidx] = lo;
}

// ---------------- MFMA GEMM (layer 0): C = (x @ W)·dinv ----------------
__global__ __launch_bounds__(256) void mfma_gemm_k(const float* __restrict__ A,
                                                   const short* __restrict__ wt_hi,
                                                   const short* __restrict__ wt_lo,
                                                   const float* __restrict__ dinv,
                                                   float* __restrict__ C, int n) {
    constexpr int NT = 8;
    const int tid = threadIdx.x;
    const int wid = tid >> 6, lane = tid & 63;
    const int arow = blockIdx.x * 64 + wid * 16 + (lane & 15);
    const int khalf = lane >> 4;

    f32x4 acc[NT];
#pragma unroll
    for (int nt = 0; nt < NT; ++nt) acc[nt] = (f32x4){0.f, 0.f, 0.f, 0.f};

#pragma unroll
    for (int kc = 0; kc < 4; ++kc) {
        const int k0 = kc * 32 + khalf * 8;
        float4 a0 = make_float4(0.f, 0.f, 0.f, 0.f), a1 = a0;
        if (arow < n) {
            a0 = *(const float4*)(A + (size_t)arow * 128 + k0);
            a1 = *(const float4*)(A + (size_t)arow * 128 + k0 + 4);
        }
        frag8 ahi, alo;
        float av[8] = {a0.x, a0.y, a0.z, a0.w, a1.x, a1.y, a1.z, a1.w};
#pragma unroll
        for (int j = 0; j < 8; ++j) split_bf16(av[j], ahi.s[j], alo.s[j]);

#pragma unroll
        for (int nt = 0; nt < NT; ++nt) {
            const size_t bidx = (size_t)(nt * 16 + (lane & 15)) * 128 + k0;
            short8 bhi = *(const short8*)(wt_hi + bidx);
            short8 blo = *(const short8*)(wt_lo + bidx);
            acc[nt] = __builtin_amdgcn_mfma_f32_16x16x32_bf16(alo.v, bhi, acc[nt], 0, 0, 0);
            acc[nt] = __builtin_amdgcn_mfma_f32_16x16x32_bf16(ahi.v, blo, acc[nt], 0, 0, 0);
            acc[nt] = __builtin_amdgcn_mfma_f32_16x16x32_bf16(ahi.v, bhi, acc[nt], 0, 0, 0);
        }
    }

    const int rbase = blockIdx.x * 64 + wid * 16 + khalf * 4;
    const int col = lane & 15;
    float dv[4];
#pragma unroll
    for (int r = 0; r < 4; ++r) dv[r] = (rbase + r < n) ? dinv[rbase + r] : 0.f;
#pragma unroll
    for (int nt = 0; nt < NT; ++nt) {
#pragma unroll
        for (int r = 0; r < 4; ++r) {
            int row = rbase + r;
            if (row < n) C[(size_t)row * 128 + nt * 16 + col] = acc[nt][r] * dv[r];
        }
    }
}

// ---------------- FUSED v9: R13 structure (8 groups x 4 nodes, float4, prefetch), padded lists ----------------
// requires NN % 32 == 0; edge lists padded to multiple of 4 -> no scalar tail
template<int HOUT>
__global__ __launch_bounds__(256) void fused_k(const float* __restrict__ tmp,
                                               const int* __restrict__ csr_src,
                                               const int2* __restrict__ rowdesc,
                                               const float* __restrict__ dinv,
                                               const float* __restrict__ bias,
                                               const short* __restrict__ wt_hi,
                                               const short* __restrict__ wt_lo,
                                               float* __restrict__ C) {
    constexpr int NT = HOUT / 32;
    __shared__ short Ah[32][136];    // bf16 hi plane
    __shared__ short Al[32][136];    // bf16 lo plane
    const int t = threadIdx.x;
    const int row0 = blockIdx.x * 32;

    // ---- phase 1: 8 groups x 4 nodes, first-chunk prefetch pipelined across nodes ----
    {
        const int l = t & 31;
        const int sub = t >> 5;
        float4 bb = *(const float4*)(bias + l * 4);
        int eptr[4], eend[4];
#pragma unroll
        for (int it = 0; it < 4; ++it) {
            int2 rd = rowdesc[row0 + it * 8 + sub];
            eptr[it] = rd.x;
            eend[it] = rd.x + rd.y;
        }
        int pf = (eptr[0] + l < eend[0]) ? csr_src[eptr[0] + l] : NN;
#pragma unroll
        for (int it = 0; it < 4; ++it) {
            const int node = row0 + it * 8 + sub;
            const float dn = dinv[node];
            float4 acc = *(const float4*)(tmp + (size_t)node * 128 + l * 4);
            int myidx = pf;
            if (it < 3)
                pf = (eptr[it + 1] + l < eend[it + 1]) ? csr_src[eptr[it + 1] + l] : NN;
            int e = eptr[it];
            const int end = eend[it];
            while (e < end) {
                int m = end - e;
                if (m > 32) m = 32;
#pragma unroll 4
                for (int j = 0; j < m; j += 4) {      // m always multiple of 4
                    int s0 = __shfl(myidx, j, 32);
                    int s1 = __shfl(myidx, j + 1, 32);
                    int s2 = __shfl(myidx, j + 2, 32);
                    int s3 = __shfl(myidx, j + 3, 32);
                    float4 v0 = *(const float4*)(tmp + (size_t)s0 * 128 + l * 4);
                    float4 v1 = *(const float4*)(tmp + (size_t)s1 * 128 + l * 4);
                    float4 v2 = *(const float4*)(tmp + (size_t)s2 * 128 + l * 4);
                    float4 v3 = *(const float4*)(tmp + (size_t)s3 * 128 + l * 4);
                    acc.x += (v0.x + v1.x) + (v2.x + v3.x);
                    acc.y += (v0.y + v1.y) + (v2.y + v3.y);
                    acc.z += (v0.z + v1.z) + (v2.z + v3.z);
                    acc.w += (v0.w + v1.w) + (v2.w + v3.w);
                }
                e += m;
                if (e < end)                           // rare continuation (deg > 32)
                    myidx = (e + l < end) ? csr_src[e + l] : NN;
            }
            acc.x = fmaxf(fmaf(acc.x, dn, bb.x), 0.f);
            acc.y = fmaxf(fmaf(acc.y, dn, bb.y), 0.f);
            acc.z = fmaxf(fmaf(acc.z, dn, bb.z), 0.f);
            acc.w = fmaxf(fmaf(acc.w, dn, bb.w), 0.f);
            short4 h4, l4;
            split_bf16(acc.x, h4.x, l4.x);
            split_bf16(acc.y, h4.y, l4.y);
            split_bf16(acc.z, h4.z, l4.z);
            split_bf16(acc.w, h4.w, l4.w);
            const int r = it * 8 + sub;
            *(short4*)&Ah[r][l * 4] = h4;
            *(short4*)&Al[r][l * 4] = l4;
        }
    }
    __syncthreads();

    // ---- phase 2: MFMA straight from bf16 LDS planes ----
    const int wid = t >> 6, lane = t & 63;
    const int rt = wid & 1;
    const int cg = wid >> 1;
    const int arow_l = rt * 16 + (lane & 15);
    const int khalf = lane >> 4;

    f32x4 acc[NT];
#pragma unroll
    for (int nt = 0; nt < NT; ++nt) acc[nt] = (f32x4){0.f, 0.f, 0.f, 0.f};

#pragma unroll
    for (int kc = 0; kc < 4; ++kc) {
        const int k0 = kc * 32 + khalf * 8;
        short8 ahi = *(const short8*)&Ah[arow_l][k0];
        short8 alo = *(const short8*)&Al[arow_l][k0];

#pragma unroll
        for (int nt = 0; nt < NT; ++nt) {
            const size_t bidx = (size_t)(cg * NT * 16 + nt * 16 + (lane & 15)) * 128 + k0;
            short8 bhi = *(const short8*)(wt_hi + bidx);
            short8 blo = *(const short8*)(wt_lo + bidx);
            acc[nt] = __builtin_amdgcn_mfma_f32_16x16x32_bf16(alo, bhi, acc[nt], 0, 0, 0);
            acc[nt] = __builtin_amdgcn_mfma_f32_16x16x32_bf16(ahi, blo, acc[nt], 0, 0, 0);
            acc[nt] = __builtin_amdgcn_mfma_f32_16x16x32_bf16(ahi, bhi, acc[nt], 0, 0, 0);
        }
    }

    const int rbase = row0 + rt * 16 + khalf * 4;
    const int col = lane & 15;
    float dv[4];
#pragma unroll
    for (int r = 0; r < 4; ++r) dv[r] = dinv[rbase + r];
#pragma unroll
    for (int nt = 0; nt < NT; ++nt) {
#pragma unroll
        for (int r = 0; r < 4; ++r) {
            C[(size_t)(rbase + r) * HOUT + cg * NT * 16 + nt * 16 + col] = acc[nt][r] * dv[r];
        }
    }
}

// ---------------- final gather-aggregate (HOUT=64): 2 nodes per 16-lane group, padded lists ----------------
__global__ __launch_bounds__(256) void agg3_k(const float* __restrict__ tmp,
                                              const int* __restrict__ csr_src,
                                              const int2* __restrict__ rowdesc,
                                              const float* __restrict__ dinv,
                                              const float* __restrict__ bias,
                                              float* __restrict__ out) {
    const int t = threadIdx.x;
    const int l = t & 15;
    const int g = t >> 4;
    const int n0 = blockIdx.x * 32 + g * 2;

    float4 bb = *(const float4*)(bias + l * 4);
    int2 rd0 = rowdesc[n0];
    int2 rd1 = rowdesc[n0 + 1];
    int eptr[2] = {rd0.x, rd1.x};
    int eend[2] = {rd0.x + rd0.y, rd1.x + rd1.y};
    int pf = (eptr[0] + l < eend[0]) ? csr_src[eptr[0] + l] : NN;

#pragma unroll
    for (int it = 0; it < 2; ++it) {
        const int node = n0 + it;
        const float dn = dinv[node];
        float4 acc = *(const float4*)(tmp + (size_t)node * 64 + l * 4);
        int myidx = pf;
        if (it < 1)
            pf = (eptr[1] + l < eend[1]) ? csr_src[eptr[1] + l] : NN;
        int e = eptr[it];
        const int end = eend[it];
        while (e < end) {
            int m = end - e;
            if (m > 16) m = 16;
#pragma unroll 4
            for (int j = 0; j < m; j += 4) {          // m always multiple of 4
                int s0 = __shfl(myidx, j, 16);
                int s1 = __shfl(myidx, j + 1, 16);
                int s2 = __shfl(myidx, j + 2, 16);
                int s3 = __shfl(myidx, j + 3, 16);
                float4 v0 = *(const float4*)(tmp + (size_t)s0 * 64 + l * 4);
                float4 v1 = *(const float4*)(tmp + (size_t)s1 * 64 + l * 4);
                float4 v2 = *(const float4*)(tmp + (size_t)s2 * 64 + l * 4);
                float4 v3 = *(const float4*)(tmp + (size_t)s3 * 64 + l * 4);
                acc.x += (v0.x + v1.x) + (v2.x + v3.x);
                acc.y += (v0.y + v1.y) + (v2.y + v3.y);
                acc.z += (v0.z + v1.z) + (v2.z + v3.z);
                acc.w += (v0.w + v1.w) + (v2.w + v3.w);
            }
            e += m;
            if (e < end)
                myidx = (e + l < end) ? csr_src[e + l] : NN;
        }
        float4 o;
        o.x = fmaf(acc.x, dn, bb.x);
        o.y = fmaf(acc.y, dn, bb.y);
        o.z = fmaf(acc.z, dn, bb.z);
        o.w = fmaf(acc.w, dn, bb.w);
        *(float4*)(out + (size_t)node * 64 + l * 4) = o;
    }
}

extern "C" void kernel_launch(void* const* d_in, const int* in_sizes, int n_in,
                              void* d_out, int out_size, void* d_ws, size_t ws_size,
                              hipStream_t stream) {
    const float* x    = (const float*)d_in[0];
    const int*   ei   = (const int*)d_in[1];
    const int*   srcp = ei;
    const int*   dstp = ei + NE;
    const float* W0 = (const float*)d_in[2]; const float* b0 = (const float*)d_in[3];
    const float* W1 = (const float*)d_in[4]; const float* b1 = (const float*)d_in[5];
    const float* W2 = (const float*)d_in[6]; const float* b2 = (const float*)d_in[7];
    const float* W3 = (const float*)d_in[8]; const float* b3 = (const float*)d_in[9];
    float* out = (float*)d_out;

    char* ws = (char*)d_ws;
    size_t off = 0;
    auto alloc = [&](size_t bytes) { void* p = ws + off; off = (off + bytes + 255) & ~(size_t)255; return p; };
    int*   bcur    = (int*)alloc((size_t)NB * 4);
    float* dinv    = (float*)alloc((size_t)NN * 4);
    int2*  rowdesc = (int2*)alloc((size_t)NN * 8);
    int*   csr_src = (int*)alloc((size_t)NB * CAP * 4);
    short* wt      = (short*)alloc((size_t)114688 * 2);
    float* bufA    = (float*)alloc((size_t)(NN + 1) * 128 * 4);   // +1 row: virtual zero node
    float* bufB    = (float*)alloc((size_t)(NN + 1) * 128 * 4);
    int2*  pairs   = (int2*)bufA;   // alias: dead before fused writes bufA

    const int nblk_e4k = (NE + 4095) / 4096;   // 391
    const int nblk_g   = (NN + 63) / 64;       // 1563
    const int nblk_f   = NN / 32;              // 3125

    // zero rows for virtual node NN (128-wide views of bufA/bufB)
    hipMemsetAsync(bufA + (size_t)NN * 128, 0, 512, stream);
    hipMemsetAsync(bufB + (size_t)NN * 128, 0, 512, stream);

    // ---- graph preprocessing: fixed-capacity bucketed CSR build (padded to 4) ----
    hipMemsetAsync(bcur, 0, (size_t)NB * 4, stream);
    part2_k<<<nblk_e4k, 256, 0, stream>>>(srcp, dstp, bcur, pairs, NE);
    csr2_k<<<NB, 256, 0, stream>>>(pairs, bcur, dinv, rowdesc, csr_src, NN);
    convw_k<<<(57344 + 255) / 256, 256, 0, stream>>>(W0, W1, W2, W3, wt);

    const short* w0h = wt,          *w0l = wt + 16384;
    const short* w1h = wt + 32768,  *w1l = wt + 49152;
    const short* w2h = wt + 65536,  *w2l = wt + 81920;
    const short* w3h = wt + 98304,  *w3l = wt + 106496;

    // layer 0 gemm: x -> tmp0 (bufB so pairs in bufA stay live until csr2 done)
    mfma_gemm_k<<<nblk_g, 256, 0, stream>>>(x, w0h, w0l, dinv, bufB, NN);
    // fused layer0-agg + layer1 gemm: tmp0 -> tmp1
    fused_k<128><<<nblk_f, 256, 0, stream>>>(bufB, csr_src, rowdesc, dinv, b0, w1h, w1l, bufA);
    // fused layer1-agg + layer2 gemm: tmp1 -> tmp2
    fused_k<128><<<nblk_f, 256, 0, stream>>>(bufA, csr_src, rowdesc, dinv, b1, w2h, w2l, bufB);
    // fused layer2-agg + layer3 gemm: tmp2 -> tmp3
    fused_k<64><<<nblk_f, 256, 0, stream>>>(bufB, csr_src, rowdesc, dinv, b2, w3h, w3l, bufA);
    // zero the 64-wide virtual row before final aggregation reads pads
    hipMemsetAsync(bufA + (size_t)NN * 64, 0, 256, stream);
    // final aggregation of tmp3 -> out
    agg3_k<<<nblk_f, 256, 0, stream>>>(bufA, csr_src, rowdesc, dinv, b3, out);
}

// Round 16
// 560.383 us; speedup vs baseline: 1.1105x; 1.0248x over previous
//
#include <hip/hip_runtime.h>
#include <math.h>

#define NN 100000
#define NE 1600000
#define NB 391    // ceil(NN/256) dst-buckets of 256 nodes
#define CAP 5120  // fixed bucket capacity incl. pad-to-4 (mean 4096+384, +8 sigma safe)

typedef __attribute__((ext_vector_type(8))) short short8;
typedef __attribute__((ext_vector_type(4))) float f32x4;

__device__ __forceinline__ void split_bf16(float a, short& hi, short& lo) {
    unsigned u = __float_as_uint(a);
    unsigned hb = u & 0xffff0000u;
    hi = (short)(hb >> 16);
    float r = a - __uint_as_float(hb);
    unsigned lu = __float_as_uint(r);
    lo = (short)((lu + 0x7fff + ((lu >> 16) & 1)) >> 16);
}

// ---------------- partition into fixed-capacity buckets, packed 4B pairs ----------------
// packed = (src << 8) | (dst & 255);  src < 2^17 so fits in 25 bits
__global__ __launch_bounds__(256) void part2_k(const int* __restrict__ src, const int* __restrict__ dst,
                                               int* bcur, int* __restrict__ pairs, int e) {
    __shared__ int lhist[NB];
    __shared__ int lbase[NB];
    int t = threadIdx.x;
    for (int i = t; i < NB; i += 256) lhist[i] = 0;
    __syncthreads();
    int e0 = blockIdx.x * 4096;
    int sreg[16], dreg[16];
#pragma unroll
    for (int j = 0; j < 16; ++j) {
        int i = e0 + j * 256 + t;
        if (i < e) {
            sreg[j] = src[i];
            dreg[j] = dst[i];
            atomicAdd(&lhist[dreg[j] >> 8], 1);
        } else dreg[j] = -1;
    }
    __syncthreads();
    for (int i = t; i < NB; i += 256) {
        int c = lhist[i];
        lbase[i] = c ? (i * CAP + atomicAdd(&bcur[i], c)) : 0;
        lhist[i] = 0;
    }
    __syncthreads();
#pragma unroll
    for (int j = 0; j < 16; ++j) {
        if (dreg[j] >= 0) {
            int b = dreg[j] >> 8;
            int pos = lbase[b] + atomicAdd(&lhist[b], 1);
            pairs[pos] = (sreg[j] << 8) | (dreg[j] & 255);
        }
    }
}

// ---------------- per-bucket (LDS-staged): count + padded scan + rowdesc/dinv + CSR fill + pad ----------------
__global__ __launch_bounds__(256) void csr2_k(const int* __restrict__ pairs, const int* __restrict__ bcur,
                                              float* __restrict__ dinv, int2* __restrict__ rowdesc,
                                              int* __restrict__ csr_src, int n) {
    __shared__ int lp[CAP];           // 20.5 KB packed
    __shared__ int cnt[256];
    __shared__ int wsum[4];
    __shared__ int lcur[256];
    int b = blockIdx.x, t = threadIdx.x;
    const int tot = bcur[b];
    const int e0 = b * CAP;
    cnt[t] = 0;
    __syncthreads();
    for (int e = t; e < tot; e += 256) {
        int p = pairs[e0 + e];
        lp[e] = p;
        atomicAdd(&cnt[p & 255], 1);
    }
    __syncthreads();
    int c = cnt[t];
    int cp = (c + 3) & ~3;            // padded to multiple of 4
    int lane = t & 63, wid = t >> 6;
    int inc = cp;
#pragma unroll
    for (int off = 1; off < 64; off <<= 1) {
        int tt = __shfl_up(inc, off);
        if (lane >= off) inc += tt;
    }
    if (lane == 63) wsum[wid] = inc;
    __syncthreads();
    int woff = 0;
    for (int w = 0; w < wid; ++w) woff += wsum[w];
    int excl = inc - cp + woff + e0;
    int i = (b << 8) + t;
    if (i < n) {
        rowdesc[i] = make_int2(excl, cp);
        dinv[i] = 1.0f / sqrtf((float)(c + 1));   // real degree
    }
    lcur[t] = excl;
    __syncthreads();
    for (int e = t; e < tot; e += 256) {
        int p = lp[e];
        int pos = atomicAdd(&lcur[p & 255], 1);
        csr_src[pos] = ((unsigned)p) >> 8;
    }
    for (int p = c; p < cp; ++p) csr_src[excl + p] = NN;   // pad with virtual zero node
}

// ---------------- W pre-split (transposed bf16 hi/lo) ----------------
__global__ __launch_bounds__(256) void convw_k(const float* __restrict__ W0, const float* __restrict__ W1,
                                               const float* __restrict__ W2, const float* __restrict__ W3,
                                               short* __restrict__ wt) {
    int gid = blockIdx.x * 256 + threadIdx.x;
    if (gid >= 57344) return;
    const float* W;
    int elem, Ncols, hi_base;
    if (gid < 49152) {
        int w = gid >> 14;
        elem = gid & 16383;
        Ncols = 128;
        W = (w == 0) ? W0 : (w == 1) ? W1 : W2;
        hi_base = w * 32768;
    } else {
        elem = gid - 49152;
        Ncols = 64;
        W = W3;
        hi_base = 98304;
    }
    int k = elem / Ncols, ncol = elem % Ncols;
    short hi, lo;
    split_bf16(W[elem], hi, lo);
    int dstidx = ncol * 128 + k;
    wt[hi_base + dstidx] = hi;
    wt[hi_base + Ncols * 128 + dstidx] = lo;
}

// ---------------- GEMM layer 0 (LDS-staged, coalesced x reads): C = (x @ W)·dinv ----------------
// requires NN % 32 == 0
__global__ __launch_bounds__(256) void gemm0_k(const float* __restrict__ A,
                                               const short* __restrict__ wt_hi,
                                               const short* __restrict__ wt_lo,
                                               const float* __restrict__ dinv,
                                               float* __restrict__ C) {
    __shared__ short Ah[32][136];
    __shared__ short Al[32][136];
    const int t = threadIdx.x;
    const int row0 = blockIdx.x * 32;

    // coalesced stage: 32 rows x 128 cols, 16B/lane consecutive
#pragma unroll
    for (int it = 0; it < 4; ++it) {
        int idx = it * 256 + t;          // 0..1023 float4 slots
        int r = idx >> 5, c4 = idx & 31;
        float4 v = *(const float4*)(A + (size_t)(row0 + r) * 128 + c4 * 4);
        short4 h4, l4;
        split_bf16(v.x, h4.x, l4.x);
        split_bf16(v.y, h4.y, l4.y);
        split_bf16(v.z, h4.z, l4.z);
        split_bf16(v.w, h4.w, l4.w);
        *(short4*)&Ah[r][c4 * 4] = h4;
        *(short4*)&Al[r][c4 * 4] = l4;
    }
    __syncthreads();

    const int wid = t >> 6, lane = t & 63;
    const int rt = wid & 1;
    const int cg = wid >> 1;
    const int arow_l = rt * 16 + (lane & 15);
    const int khalf = lane >> 4;

    f32x4 acc[4];
#pragma unroll
    for (int nt = 0; nt < 4; ++nt) acc[nt] = (f32x4){0.f, 0.f, 0.f, 0.f};

#pragma unroll
    for (int kc = 0; kc < 4; ++kc) {
        const int k0 = kc * 32 + khalf * 8;
        short8 ahi = *(const short8*)&Ah[arow_l][k0];
        short8 alo = *(const short8*)&Al[arow_l][k0];
#pragma unroll
        for (int nt = 0; nt < 4; ++nt) {
            const size_t bidx = (size_t)(cg * 64 + nt * 16 + (lane & 15)) * 128 + k0;
            short8 bhi = *(const short8*)(wt_hi + bidx);
            short8 blo = *(const short8*)(wt_lo + bidx);
            acc[nt] = __builtin_amdgcn_mfma_f32_16x16x32_bf16(alo, bhi, acc[nt], 0, 0, 0);
            acc[nt] = __builtin_amdgcn_mfma_f32_16x16x32_bf16(ahi, blo, acc[nt], 0, 0, 0);
            acc[nt] = __builtin_amdgcn_mfma_f32_16x16x32_bf16(ahi, bhi, acc[nt], 0, 0, 0);
        }
    }

    const int rbase = row0 + rt * 16 + khalf * 4;
    const int col = lane & 15;
    float dv[4];
#pragma unroll
    for (int r = 0; r < 4; ++r) dv[r] = dinv[rbase + r];
#pragma unroll
    for (int nt = 0; nt < 4; ++nt) {
#pragma unroll
        for (int r = 0; r < 4; ++r) {
            C[(size_t)(rbase + r) * 128 + cg * 64 + nt * 16 + col] = acc[nt][r] * dv[r];
        }
    }
}

// ---------------- FUSED v9: 8 groups x 4 nodes, float4, prefetch, padded lists ----------------
template<int HOUT>
__global__ __launch_bounds__(256) void fused_k(const float* __restrict__ tmp,
                                               const int* __restrict__ csr_src,
                                               const int2* __restrict__ rowdesc,
                                               const float* __restrict__ dinv,
                                               const float* __restrict__ bias,
                                               const short* __restrict__ wt_hi,
                                               const short* __restrict__ wt_lo,
                                               float* __restrict__ C) {
    constexpr int NT = HOUT / 32;
    __shared__ short Ah[32][136];
    __shared__ short Al[32][136];
    const int t = threadIdx.x;
    const int row0 = blockIdx.x * 32;

    {
        const int l = t & 31;
        const int sub = t >> 5;
        float4 bb = *(const float4*)(bias + l * 4);
        int eptr[4], eend[4];
#pragma unroll
        for (int it = 0; it < 4; ++it) {
            int2 rd = rowdesc[row0 + it * 8 + sub];
            eptr[it] = rd.x;
            eend[it] = rd.x + rd.y;
        }
        int pf = (eptr[0] + l < eend[0]) ? csr_src[eptr[0] + l] : NN;
#pragma unroll
        for (int it = 0; it < 4; ++it) {
            const int node = row0 + it * 8 + sub;
            const float dn = dinv[node];
            float4 acc = *(const float4*)(tmp + (size_t)node * 128 + l * 4);
            int myidx = pf;
            if (it < 3)
                pf = (eptr[it + 1] + l < eend[it + 1]) ? csr_src[eptr[it + 1] + l] : NN;
            int e = eptr[it];
            const int end = eend[it];
            while (e < end) {
                int m = end - e;
                if (m > 32) m = 32;
#pragma unroll 4
                for (int j = 0; j < m; j += 4) {
                    int s0 = __shfl(myidx, j, 32);
                    int s1 = __shfl(myidx, j + 1, 32);
                    int s2 = __shfl(myidx, j + 2, 32);
                    int s3 = __shfl(myidx, j + 3, 32);
                    float4 v0 = *(const float4*)(tmp + (size_t)s0 * 128 + l * 4);
                    float4 v1 = *(const float4*)(tmp + (size_t)s1 * 128 + l * 4);
                    float4 v2 = *(const float4*)(tmp + (size_t)s2 * 128 + l * 4);
                    float4 v3 = *(const float4*)(tmp + (size_t)s3 * 128 + l * 4);
                    acc.x += (v0.x + v1.x) + (v2.x + v3.x);
                    acc.y += (v0.y + v1.y) + (v2.y + v3.y);
                    acc.z += (v0.z + v1.z) + (v2.z + v3.z);
                    acc.w += (v0.w + v1.w) + (v2.w + v3.w);
                }
                e += m;
                if (e < end)
                    myidx = (e + l < end) ? csr_src[e + l] : NN;
            }
            acc.x = fmaxf(fmaf(acc.x, dn, bb.x), 0.f);
            acc.y = fmaxf(fmaf(acc.y, dn, bb.y), 0.f);
            acc.z = fmaxf(fmaf(acc.z, dn, bb.z), 0.f);
            acc.w = fmaxf(fmaf(acc.w, dn, bb.w), 0.f);
            short4 h4, l4;
            split_bf16(acc.x, h4.x, l4.x);
            split_bf16(acc.y, h4.y, l4.y);
            split_bf16(acc.z, h4.z, l4.z);
            split_bf16(acc.w, h4.w, l4.w);
            const int r = it * 8 + sub;
            *(short4*)&Ah[r][l * 4] = h4;
            *(short4*)&Al[r][l * 4] = l4;
        }
    }
    __syncthreads();

    const int wid = t >> 6, lane = t & 63;
    const int rt = wid & 1;
    const int cg = wid >> 1;
    const int arow_l = rt * 16 + (lane & 15);
    const int khalf = lane >> 4;

    f32x4 acc[NT];
#pragma unroll
    for (int nt = 0; nt < NT; ++nt) acc[nt] = (f32x4){0.f, 0.f, 0.f, 0.f};

#pragma unroll
    for (int kc = 0; kc < 4; ++kc) {
        const int k0 = kc * 32 + khalf * 8;
        short8 ahi = *(const short8*)&Ah[arow_l][k0];
        short8 alo = *(const short8*)&Al[arow_l][k0];
#pragma unroll
        for (int nt = 0; nt < NT; ++nt) {
            const size_t bidx = (size_t)(cg * NT * 16 + nt * 16 + (lane & 15)) * 128 + k0;
            short8 bhi = *(const short8*)(wt_hi + bidx);
            short8 blo = *(const short8*)(wt_lo + bidx);
            acc[nt] = __builtin_amdgcn_mfma_f32_16x16x32_bf16(alo, bhi, acc[nt], 0, 0, 0);
            acc[nt] = __builtin_amdgcn_mfma_f32_16x16x32_bf16(ahi, blo, acc[nt], 0, 0, 0);
            acc[nt] = __builtin_amdgcn_mfma_f32_16x16x32_bf16(ahi, bhi, acc[nt], 0, 0, 0);
        }
    }

    const int rbase = row0 + rt * 16 + khalf * 4;
    const int col = lane & 15;
    float dv[4];
#pragma unroll
    for (int r = 0; r < 4; ++r) dv[r] = dinv[rbase + r];
#pragma unroll
    for (int nt = 0; nt < NT; ++nt) {
#pragma unroll
        for (int r = 0; r < 4; ++r) {
            C[(size_t)(rbase + r) * HOUT + cg * NT * 16 + nt * 16 + col] = acc[nt][r] * dv[r];
        }
    }
}

// ---------------- final gather-aggregate (HOUT=64): 2 nodes per 16-lane group, padded lists ----------------
__global__ __launch_bounds__(256) void agg3_k(const float* __restrict__ tmp,
                                              const int* __restrict__ csr_src,
                                              const int2* __restrict__ rowdesc,
                                              const float* __restrict__ dinv,
                                              const float* __restrict__ bias,
                                              float* __restrict__ out) {
    const int t = threadIdx.x;
    const int l = t & 15;
    const int g = t >> 4;
    const int n0 = blockIdx.x * 32 + g * 2;

    float4 bb = *(const float4*)(bias + l * 4);
    int2 rd0 = rowdesc[n0];
    int2 rd1 = rowdesc[n0 + 1];
    int eptr[2] = {rd0.x, rd1.x};
    int eend[2] = {rd0.x + rd0.y, rd1.x + rd1.y};
    int pf = (eptr[0] + l < eend[0]) ? csr_src[eptr[0] + l] : NN;

#pragma unroll
    for (int it = 0; it < 2; ++it) {
        const int node = n0 + it;
        const float dn = dinv[node];
        float4 acc = *(const float4*)(tmp + (size_t)node * 64 + l * 4);
        int myidx = pf;
        if (it < 1)
            pf = (eptr[1] + l < eend[1]) ? csr_src[eptr[1] + l] : NN;
        int e = eptr[it];
        const int end = eend[it];
        while (e < end) {
            int m = end - e;
            if (m > 16) m = 16;
#pragma unroll 4
            for (int j = 0; j < m; j += 4) {
                int s0 = __shfl(myidx, j, 16);
                int s1 = __shfl(myidx, j + 1, 16);
                int s2 = __shfl(myidx, j + 2, 16);
                int s3 = __shfl(myidx, j + 3, 16);
                float4 v0 = *(const float4*)(tmp + (size_t)s0 * 64 + l * 4);
                float4 v1 = *(const float4*)(tmp + (size_t)s1 * 64 + l * 4);
                float4 v2 = *(const float4*)(tmp + (size_t)s2 * 64 + l * 4);
                float4 v3 = *(const float4*)(tmp + (size_t)s3 * 64 + l * 4);
                acc.x += (v0.x + v1.x) + (v2.x + v3.x);
                acc.y += (v0.y + v1.y) + (v2.y + v3.y);
                acc.z += (v0.z + v1.z) + (v2.z + v3.z);
                acc.w += (v0.w + v1.w) + (v2.w + v3.w);
            }
            e += m;
            if (e < end)
                myidx = (e + l < end) ? csr_src[e + l] : NN;
        }
        float4 o;
        o.x = fmaf(acc.x, dn, bb.x);
        o.y = fmaf(acc.y, dn, bb.y);
        o.z = fmaf(acc.z, dn, bb.z);
        o.w = fmaf(acc.w, dn, bb.w);
        *(float4*)(out + (size_t)node * 64 + l * 4) = o;
    }
}

extern "C" void kernel_launch(void* const* d_in, const int* in_sizes, int n_in,
                              void* d_out, int out_size, void* d_ws, size_t ws_size,
                              hipStream_t stream) {
    const float* x    = (const float*)d_in[0];
    const int*   ei   = (const int*)d_in[1];
    const int*   srcp = ei;
    const int*   dstp = ei + NE;
    const float* W0 = (const float*)d_in[2]; const float* b0 = (const float*)d_in[3];
    const float* W1 = (const float*)d_in[4]; const float* b1 = (const float*)d_in[5];
    const float* W2 = (const float*)d_in[6]; const float* b2 = (const float*)d_in[7];
    const float* W3 = (const float*)d_in[8]; const float* b3 = (const float*)d_in[9];
    float* out = (float*)d_out;

    char* ws = (char*)d_ws;
    size_t off = 0;
    auto alloc = [&](size_t bytes) { void* p = ws + off; off = (off + bytes + 255) & ~(size_t)255; return p; };
    int*   bcur    = (int*)alloc((size_t)NB * 4);
    float* dinv    = (float*)alloc((size_t)NN * 4);
    int2*  rowdesc = (int2*)alloc((size_t)NN * 8);
    int*   csr_src = (int*)alloc((size_t)NB * CAP * 4);
    short* wt      = (short*)alloc((size_t)114688 * 2);
    float* bufA    = (float*)alloc((size_t)(NN + 1) * 128 * 4);   // +1 row: virtual zero node
    float* bufB    = (float*)alloc((size_t)(NN + 1) * 128 * 4);
    int*   pairs   = (int*)bufA;   // alias: dead before fused writes bufA

    const int nblk_e4k = (NE + 4095) / 4096;   // 391
    const int nblk_f   = NN / 32;              // 3125

    // zero rows for virtual node NN (128-wide views of bufA/bufB)
    hipMemsetAsync(bufA + (size_t)NN * 128, 0, 512, stream);
    hipMemsetAsync(bufB + (size_t)NN * 128, 0, 512, stream);

    // ---- graph preprocessing: fixed-capacity bucketed CSR build (packed pairs, padded to 4) ----
    hipMemsetAsync(bcur, 0, (size_t)NB * 4, stream);
    part2_k<<<nblk_e4k, 256, 0, stream>>>(srcp, dstp, bcur, pairs, NE);
    csr2_k<<<NB, 256, 0, stream>>>(pairs, bcur, dinv, rowdesc, csr_src, NN);
    convw_k<<<(57344 + 255) / 256, 256, 0, stream>>>(W0, W1, W2, W3, wt);

    const short* w0h = wt,          *w0l = wt + 16384;
    const short* w1h = wt + 32768,  *w1l = wt + 49152;
    const short* w2h = wt + 65536,  *w2l = wt + 81920;
    const short* w3h = wt + 98304,  *w3l = wt + 106496;

    // layer 0 gemm (coalesced LDS staging): x -> tmp0 (bufB; pairs in bufA live until csr2 done)
    gemm0_k<<<nblk_f, 256, 0, stream>>>(x, w0h, w0l, dinv, bufB);
    // fused layer0-agg + layer1 gemm: tmp0 -> tmp1
    fused_k<128><<<nblk_f, 256, 0, stream>>>(bufB, csr_src, rowdesc, dinv, b0, w1h, w1l, bufA);
    // fused layer1-agg + layer2 gemm: tmp1 -> tmp2
    fused_k<128><<<nblk_f, 256, 0, stream>>>(bufA, csr_src, rowdesc, dinv, b1, w2h, w2l, bufB);
    // fused layer2-agg + layer3 gemm: tmp2 -> tmp3
    fused_k<64><<<nblk_f, 256, 0, stream>>>(bufB, csr_src, rowdesc, dinv, b2, w3h, w3l, bufA);
    // zero the 64-wide virtual row before final aggregation reads pads
    hipMemsetAsync(bufA + (size_t)NN * 64, 0, 256, stream);
    // final aggregation of tmp3 -> out
    agg3_k<<<nblk_f, 256, 0, stream>>>(bufA, csr_src, rowdesc, dinv, b3, out);
}